// Round 11
// baseline (982.820 us; speedup 1.0000x reference)
//
#include <hip/hip_runtime.h>

typedef __attribute__((ext_vector_type(4))) float f32x4;
typedef __attribute__((ext_vector_type(8))) short s16x8;
typedef unsigned short u16;
typedef unsigned int u32;

// ---------- helpers ----------
__device__ __forceinline__ u16 f2bf(float f){
  u32 u = __builtin_bit_cast(u32, f);
  u += 0x7fffu + ((u >> 16) & 1u);          // RNE
  return (u16)(u >> 16);
}
__device__ __forceinline__ float gelu_exact(float x){
  return 0.5f * x * (1.0f + erff(x * 0.70710678118654752f));
}
__device__ __forceinline__ float sigmoidf_(float x){
  return 1.0f / (1.0f + expf(-x));
}

// inline-asm LDS read: opaque to the compiler's waitcnt pass (prevents it from
// inserting vmcnt(0) drains for the global_load_lds RAW hazard).
template<int OFF>
__device__ __forceinline__ s16x8 dsr(u32 addr){
  s16x8 r;
  asm volatile("ds_read_b128 %0, %1 offset:%2" : "=v"(r) : "v"(addr), "i"(OFF));
  return r;
}
// guaranteed LDS byte offset (ptrtoint of an addrspace(3) pointer)
__device__ __forceinline__ u32 lds_off(const void* p){
  return (u32)(size_t)(const __attribute__((address_space(3))) char*)p;
}
template<int N> __device__ __forceinline__ void vmw(){
  asm volatile("s_waitcnt vmcnt(%0)" :: "n"(N) : "memory");
}
template<int N> __device__ __forceinline__ void lgw(){
  asm volatile("s_waitcnt lgkmcnt(%0)" :: "n"(N) : "memory");
}
template<int N> struct icv { static constexpr int v = N; };
template<bool B> struct bcv { static constexpr bool v = B; };

// 256-thread block reductions (4 waves)
__device__ __forceinline__ float blk_sum(float v, float* red){
  #pragma unroll
  for (int off = 32; off; off >>= 1) v += __shfl_xor(v, off, 64);
  int t = threadIdx.x;
  if ((t & 63) == 0) red[t >> 6] = v;
  __syncthreads();
  float r = red[0] + red[1] + red[2] + red[3];
  __syncthreads();
  return r;
}
__device__ __forceinline__ float blk_max(float v, float* red){
  #pragma unroll
  for (int off = 32; off; off >>= 1) v = fmaxf(v, __shfl_xor(v, off, 64));
  int t = threadIdx.x;
  if ((t & 63) == 0) red[t >> 6] = v;
  __syncthreads();
  float r = fmaxf(fmaxf(red[0], red[1]), fmaxf(red[2], red[3]));
  __syncthreads();
  return r;
}

// ---------- transpose + elementwise (fp32 in -> bf16/fp32 out), strided dest ----------
enum { OPC_CAST = 0, OPC_SIG2M1 = 2 };

template<int OP, typename OutT>
__global__ __launch_bounds__(256) void transpose_op(const float* __restrict__ in,
                                                    OutT* __restrict__ out, int R, int C,
                                                    int ldo){
  __shared__ float tile[64][65];
  const int tc = blockIdx.x, tr = blockIdx.y;
  const int c = threadIdx.x & 63, r4 = threadIdx.x >> 6;
  #pragma unroll
  for (int i = 0; i < 16; i++){
    int r = r4 * 16 + i;
    float v = in[(size_t)(tr * 64 + r) * C + tc * 64 + c];
    if (OP == OPC_SIG2M1) v = 2.0f * sigmoidf_(v) - 1.0f;
    tile[r][c] = v;
  }
  __syncthreads();
  #pragma unroll
  for (int i = 0; i < 16; i++){
    int r = r4 * 16 + i;
    float v = tile[c][r];
    size_t o = (size_t)(tc * 64 + r) * ldo + tr * 64 + c;
    if constexpr (sizeof(OutT) == 2) out[o] = f2bf(v);
    else                             out[o] = v;
  }
}

// transpose W1 [R][C] fp32 -> bf16 [C][R] AND accumulate column sums into SCOL[C]
__global__ __launch_bounds__(256) void transpose_sum(const float* __restrict__ in,
                                                     u16* __restrict__ out, int R, int C,
                                                     float* __restrict__ SCOL){
  __shared__ float tile[64][65];
  const int tc = blockIdx.x, tr = blockIdx.y;
  const int c = threadIdx.x & 63, r4 = threadIdx.x >> 6;
  float part = 0.f;
  #pragma unroll
  for (int i = 0; i < 16; i++){
    int r = r4 * 16 + i;
    float v = in[(size_t)(tr * 64 + r) * C + tc * 64 + c];
    tile[r][c] = v;
    part += v;
  }
  __syncthreads();
  #pragma unroll
  for (int i = 0; i < 16; i++){
    int r = r4 * 16 + i;
    out[(size_t)(tc * 64 + r) * R + tr * 64 + c] = f2bf(tile[c][r]);
  }
  __syncthreads();
  tile[r4][c] = part;
  __syncthreads();
  if (r4 == 0){
    float s = tile[0][c] + tile[1][c] + tile[2][c] + tile[3][c];
    atomicAdd(&SCOL[tc * 64 + c], s);
  }
}

// elementwise sigmoid(x)-0.5 -> bf16 (natural layout)
__global__ __launch_bounds__(256) void sig05_kernel(const float* __restrict__ in,
                                                    u16* __restrict__ out){
  int i = (blockIdx.x * 256 + threadIdx.x) * 4;
  const float4 v = *(const float4*)(in + i);
  ushort4 o;
  o.x = f2bf(sigmoidf_(v.x) - 0.5f); o.y = f2bf(sigmoidf_(v.y) - 0.5f);
  o.z = f2bf(sigmoidf_(v.z) - 0.5f); o.w = f2bf(sigmoidf_(v.w) - 0.5f);
  *(ushort4*)(out + i) = o;
}

__global__ __launch_bounds__(256) void sk_fill(float* p, int n, float v){
  int i = blockIdx.x * 256 + threadIdx.x;
  if (i < n) p[i] = v;
}

// ---------- sinkhorn ----------
__global__ __launch_bounds__(256) void sk_softmax_k(const float* __restrict__ raw,
                                                    float* __restrict__ A0){
  __shared__ float red[4];
  const int row = blockIdx.x, t = threadIdx.x;
  const float4 v = *(const float4*)(raw + (size_t)row * 1024 + t * 4);
  float mx = fmaxf(fmaxf(v.x, v.y), fmaxf(v.z, v.w));
  mx = blk_max(mx, red);
  float e0 = expf(v.x - mx), e1 = expf(v.y - mx), e2 = expf(v.z - mx), e3 = expf(v.w - mx);
  float s = blk_sum(e0 + e1 + e2 + e3, red);
  float sc = 1024.0f / s;
  float4 o = { e0 * sc, e1 * sc, e2 * sc, e3 * sc };
  *(float4*)(A0 + (size_t)row * 1024 + t * 4) = o;
}

// vupd[row] = vupd[row] / (vupd[row]*dot(Am[row,:], vin) + 1e-8)
__global__ __launch_bounds__(256) void sk_pass(const float* __restrict__ Am,
                                               const float* __restrict__ vin,
                                               float* __restrict__ vupd){
  __shared__ float red[4];
  const int row = blockIdx.x, t = threadIdx.x;
  const float4 a = *(const float4*)(Am + (size_t)row * 1024 + t * 4);
  const float4 b = *(const float4*)(vin + t * 4);
  float d = a.x * b.x + a.y * b.y + a.z * b.z + a.w * b.w;
  d = blk_sum(d, red);
  if (t == 0){ float rv = vupd[row]; vupd[row] = rv / (rv * d + 1e-8f); }
}

// BCAT[e][d] (stride ld) = bf16(r[d] * A0T[e][d] * c[e])
__global__ __launch_bounds__(256) void sk_mat(const float* __restrict__ A0T,
                                              const float* __restrict__ r,
                                              const float* __restrict__ c,
                                              u16* __restrict__ dst, int ld){
  const int e = blockIdx.x, t = threadIdx.x;
  const float ce = c[e];
  const float4 a  = *(const float4*)(A0T + (size_t)e * 1024 + t * 4);
  const float4 rv = *(const float4*)(r + t * 4);
  ushort4 o;
  o.x = f2bf(a.x * rv.x * ce); o.y = f2bf(a.y * rv.y * ce);
  o.z = f2bf(a.z * rv.z * ce); o.w = f2bf(a.w * rv.w * ce);
  *(ushort4*)(dst + (size_t)e * ld + t * 4) = o;
}

// ---------- layernorms ----------
__global__ __launch_bounds__(256) void ln1_kernel(const float* __restrict__ x,
    const float* __restrict__ g, const float* __restrict__ b,
    u16* __restrict__ xn, u16* __restrict__ xbf, int xstride,
    float* __restrict__ sOut){
  __shared__ float red[4];
  const int row = blockIdx.x, t = threadIdx.x;
  const float4 v = *(const float4*)(x + (size_t)row * 1024 + t * 4);
  float mu = blk_sum(v.x + v.y + v.z + v.w, red) * (1.0f / 1024.0f);
  float d0 = v.x - mu, d1 = v.y - mu, d2 = v.z - mu, d3 = v.w - mu;
  float var = blk_sum(d0 * d0 + d1 * d1 + d2 * d2 + d3 * d3, red) * (1.0f / 1024.0f);
  float rstd = rsqrtf(var + 1e-5f);
  const float4 gv = *(const float4*)(g + t * 4);
  const float4 bv = *(const float4*)(b + t * 4);
  float y0 = d0 * rstd * gv.x + bv.x;
  float y1 = d1 * rstd * gv.y + bv.y;
  float y2 = d2 * rstd * gv.z + bv.z;
  float y3 = d3 * rstd * gv.w + bv.w;
  float ss = blk_sum(y0 + y1 + y2 + y3, red);   // fp32 row-sum of xn (rank-1 epilogue term)
  if (t == 0) sOut[row] = ss;
  ushort4 o;  o.x = f2bf(y0);  o.y = f2bf(y1);  o.z = f2bf(y2);  o.w = f2bf(y3);
  *(ushort4*)(xn + (size_t)row * 1024 + t * 4) = o;
  ushort4 xo; xo.x = f2bf(v.x); xo.y = f2bf(v.y); xo.z = f2bf(v.z); xo.w = f2bf(v.w);
  *(ushort4*)(xbf + (size_t)row * xstride + t * 4) = xo;
}

__global__ __launch_bounds__(256) void ln2_kernel(const float* __restrict__ y,
    const float* __restrict__ g, const float* __restrict__ b, float* __restrict__ out){
  __shared__ float red[4];
  const int row = blockIdx.x, t = threadIdx.x;
  const float4 v = *(const float4*)(y + (size_t)row * 1024 + t * 4);
  float mu = blk_sum(v.x + v.y + v.z + v.w, red) * (1.0f / 1024.0f);
  float d0 = v.x - mu, d1 = v.y - mu, d2 = v.z - mu, d3 = v.w - mu;
  float var = blk_sum(d0 * d0 + d1 * d1 + d2 * d2 + d3 * d3, red) * (1.0f / 1024.0f);
  float rstd = rsqrtf(var + 1e-5f);
  const float4 gv = *(const float4*)(g + t * 4);
  const float4 bv = *(const float4*)(b + t * 4);
  float4 o = { d0 * rstd * gv.x + bv.x, d1 * rstd * gv.y + bv.y,
               d2 * rstd * gv.z + bv.z, d3 * rstd * gv.w + bv.w };
  *(float4*)(out + (size_t)row * 1024 + t * 4) = o;
}

enum { EPI_GELU = 1, EPI_F32 = 2, EPI_ADDF32 = 3, EPI_BF16 = 4, EPI_GELU2 = 5 };

__device__ __forceinline__ void gload16(const void* g, void* l){
  __builtin_amdgcn_global_load_lds((const __attribute__((address_space(1))) u32*)g,
                                   (__attribute__((address_space(3))) u32*)l, 16, 0, 0);
}

// ---------- 256x256 GEMM, 8 waves — m201-template phase skeleton ----------
// Per tile t, 4 phases; each phase: {stage 2 rounds; issue this phase's ds_reads;
// [counted vmw pre-barrier]; s_barrier; lgkmcnt(0); setprio(1) 16 MFMA setprio(0);
// s_barrier}. ds latency hides under the barrier join (reads pre-barrier, wait
// post-barrier). Stages: PH0 A23(t+1)->qb, PH1 A01(t+2)->pb, PH2 B01(t+2)->pb,
// PH3 B23(t+2)->pb. vmw<8> at PH1 (retires A23(t),A01(t+1) for PH2's a1) and PH3
// (retires B01,B23(t+1) for next tile). Steady in-flight 8..12, never drained.
// Tails: NT-2={6,2}, NT-1={0,skip}. Prologue 14 rounds -> vmw<8>.
template<int EPI>
__global__ __launch_bounds__(512, 2) void gemm8(const u16* __restrict__ A,
    const u16* __restrict__ BT, int K, int ldc,
    u16* __restrict__ obf, float* __restrict__ ofp,
    const float* __restrict__ bcol, const float* __restrict__ brow,
    const float* __restrict__ bcol2){
  __shared__ __align__(16) u16 lsA[2 * 256 * 64];
  __shared__ __align__(16) u16 lsB[2 * 256 * 64];
  const int tid = threadIdx.x;
  const int lane = tid & 63;
  const int wave = tid >> 6;

  // bijective XCD swizzle (all grids here are %8==0)
  const u32 gx = gridDim.x;
  const u32 nwg = gx * gridDim.y;
  const u32 orig = blockIdx.y * gx + blockIdx.x;
  const u32 swzid = (orig & 7) * (nwg >> 3) + (orig >> 3);
  const int br = (int)(swzid / gx) * 256;
  const int bc = (int)(swzid % gx) * 256;

  const int wr  = (wave >> 2) * 128;
  const int wc_ = (wave & 3) * 64;

  const int fr = lane & 15;
  const int colb0 = (lane >> 4) * 16;
  const int swz = colb0 ^ ((fr & 7) << 4);
  const u32 baseA = lds_off(lsA);
  const u32 baseB = lds_off(lsB);
  const u32 sA0 = baseA + (u32)((wr + fr) * 128 + swz);
  const u32 sA1 = baseA + (u32)((wr + fr) * 128 + (swz ^ 64));
  const u32 sB0 = baseB + (u32)((wc_ + fr) * 128 + swz);
  const u32 sB1 = baseB + (u32)((wc_ + fr) * 128 + (swz ^ 64));

  const int r = tid >> 3, s = tid & 7;
  const int lc8 = ((s ^ (r & 7)) * 8);
  const int rb_ = (r & 31) + ((r >> 5) << 6);
  const int rA[4] = { r, r + 128, r + 64, r + 192 };
  const int rB[4] = { rb_, rb_ + 128, rb_ + 32, rb_ + 160 };
  u32 srcA[4], srcB[4], dstA[4], dstB[4];
  #pragma unroll
  for (int i = 0; i < 4; i++){
    srcA[i] = (u32)(br + rA[i]) * (u32)K + (u32)lc8;
    srcB[i] = (u32)(bc + rB[i]) * (u32)K + (u32)lc8;
    dstA[i] = (u32)(rA[i] * 128 + s * 16);
    dstB[i] = (u32)(rB[i] * 128 + s * 16);
  }
  auto stA = [&](int i, u32 koff, u32 qb){ gload16(A  + srcA[i] + koff, (char*)lsA + qb + dstA[i]); };
  auto stB = [&](int i, u32 koff, u32 qb){ gload16(BT + srcB[i] + koff, (char*)lsB + qb + dstB[i]); };

  const int NT = K >> 6;
  f32x4 acc[8][4] = {};

  auto tile_body = [&](int t, auto W1_, auto W3_, auto ST0_, auto STR_){
    constexpr int  W1v  = decltype(W1_)::v;
    constexpr int  W3v  = decltype(W3_)::v;
    constexpr bool ST0  = decltype(ST0_)::v;
    constexpr bool STR  = decltype(STR_)::v;
    const u32 pb = (t & 1) ? 32768u : 0u;
    const u32 qb = pb ^ 32768u;
    const u32 k1 = (u32)(t + 1) << 6;
    const u32 k2 = (u32)(t + 2) << 6;
    const u32 aA0 = sA0 + pb, aA1 = sA1 + pb, bB0 = sB0 + pb, bB1 = sB1 + pb;
    s16x8 a0[4][2], a1[4][2], b0[2][2], b1[2][2];

    // ---- PH0: stage A23(t+1)->qb; issue a0(8)+b0(4); lgkm(8) drain; BAR; lgkm(0); Q00
    if constexpr (ST0){ stA(2, k1, qb); stA(3, k1, qb); }
    a0[0][0] = dsr<0>(aA0);    a0[0][1] = dsr<0>(aA1);
    a0[1][0] = dsr<2048>(aA0); a0[1][1] = dsr<2048>(aA1);
    a0[2][0] = dsr<4096>(aA0); a0[2][1] = dsr<4096>(aA1);
    a0[3][0] = dsr<6144>(aA0); a0[3][1] = dsr<6144>(aA1);
    b0[0][0] = dsr<0>(bB0);    b0[0][1] = dsr<0>(bB1);
    b0[1][0] = dsr<2048>(bB0); b0[1][1] = dsr<2048>(bB1);
    lgw<8>();
    __builtin_amdgcn_sched_barrier(0);
    __builtin_amdgcn_s_barrier();
    lgw<0>();
    __builtin_amdgcn_sched_barrier(0);
    __builtin_amdgcn_s_setprio(1);
    #pragma unroll
    for (int kk = 0; kk < 2; kk++)
      #pragma unroll
      for (int m = 0; m < 4; m++)
        #pragma unroll
        for (int n = 0; n < 2; n++)
          acc[m][n] = __builtin_amdgcn_mfma_f32_16x16x32_bf16(a0[m][kk], b0[n][kk], acc[m][n], 0, 0, 0);
    __builtin_amdgcn_s_setprio(0);
    __builtin_amdgcn_sched_barrier(0);
    __builtin_amdgcn_s_barrier();
    __builtin_amdgcn_sched_barrier(0);

    // ---- PH1: stage A01(t+2)->pb; issue b1(4); vmw<W1> publishes A23(t),A01(t+1); BAR; Q01
    if constexpr (STR){ stA(0, k2, pb); stA(1, k2, pb); }
    b1[0][0] = dsr<4096>(bB0); b1[0][1] = dsr<4096>(bB1);
    b1[1][0] = dsr<6144>(bB0); b1[1][1] = dsr<6144>(bB1);
    vmw<W1v < 0 ? 0 : W1v>();
    __builtin_amdgcn_sched_barrier(0);
    __builtin_amdgcn_s_barrier();
    lgw<0>();
    __builtin_amdgcn_sched_barrier(0);
    __builtin_amdgcn_s_setprio(1);
    #pragma unroll
    for (int kk = 0; kk < 2; kk++)
      #pragma unroll
      for (int m = 0; m < 4; m++)
        #pragma unroll
        for (int n = 0; n < 2; n++)
          acc[m][n + 2] = __builtin_amdgcn_mfma_f32_16x16x32_bf16(a0[m][kk], b1[n][kk], acc[m][n + 2], 0, 0, 0);
    __builtin_amdgcn_s_setprio(0);
    __builtin_amdgcn_sched_barrier(0);
    __builtin_amdgcn_s_barrier();
    __builtin_amdgcn_sched_barrier(0);

    // ---- PH2: stage B01(t+2)->pb; issue a1(8); BAR; lgkm(0); Q11
    if constexpr (STR){ stB(0, k2, pb); stB(1, k2, pb); }
    a1[0][0] = dsr<8192>(aA0);  a1[0][1] = dsr<8192>(aA1);
    a1[1][0] = dsr<10240>(aA0); a1[1][1] = dsr<10240>(aA1);
    a1[2][0] = dsr<12288>(aA0); a1[2][1] = dsr<12288>(aA1);
    a1[3][0] = dsr<14336>(aA0); a1[3][1] = dsr<14336>(aA1);
    __builtin_amdgcn_sched_barrier(0);
    __builtin_amdgcn_s_barrier();
    lgw<0>();
    __builtin_amdgcn_sched_barrier(0);
    __builtin_amdgcn_s_setprio(1);
    #pragma unroll
    for (int kk = 0; kk < 2; kk++)
      #pragma unroll
      for (int m = 0; m < 4; m++)
        #pragma unroll
        for (int n = 0; n < 2; n++)
          acc[m + 4][n + 2] = __builtin_amdgcn_mfma_f32_16x16x32_bf16(a1[m][kk], b1[n][kk], acc[m + 4][n + 2], 0, 0, 0);
    __builtin_amdgcn_s_setprio(0);
    __builtin_amdgcn_sched_barrier(0);
    __builtin_amdgcn_s_barrier();
    __builtin_amdgcn_sched_barrier(0);

    // ---- PH3: stage B23(t+2)->pb; vmw<W3> publishes B01,B23(t+1); BAR; Q10 (regs)
    if constexpr (STR){ stB(2, k2, pb); stB(3, k2, pb); }
    if constexpr (W3v >= 0){
      vmw<W3v>();
    }
    __builtin_amdgcn_sched_barrier(0);
    __builtin_amdgcn_s_barrier();
    __builtin_amdgcn_sched_barrier(0);
    __builtin_amdgcn_s_setprio(1);
    #pragma unroll
    for (int kk = 0; kk < 2; kk++)
      #pragma unroll
      for (int m = 0; m < 4; m++)
        #pragma unroll
        for (int n = 0; n < 2; n++)
          acc[m + 4][n] = __builtin_amdgcn_mfma_f32_16x16x32_bf16(a1[m][kk], b0[n][kk], acc[m + 4][n], 0, 0, 0);
    __builtin_amdgcn_s_setprio(0);
    __builtin_amdgcn_sched_barrier(0);
    __builtin_amdgcn_s_barrier();
    __builtin_amdgcn_sched_barrier(0);
  };

  // prologue: {A01,B01,B23}(0) then {A23(0), A01,B01,B23(1)}; retire the first 6
  stA(0, 0, 0); stA(1, 0, 0); stB(0, 0, 0); stB(1, 0, 0);
  stB(2, 0, 0); stB(3, 0, 0);
  stA(2, 0, 0); stA(3, 0, 0);
  stA(0, 64, 32768u); stA(1, 64, 32768u); stB(0, 64, 32768u); stB(1, 64, 32768u);
  stB(2, 64, 32768u); stB(3, 64, 32768u);
  vmw<8>();
  __builtin_amdgcn_sched_barrier(0);
  __builtin_amdgcn_s_barrier();
  __builtin_amdgcn_sched_barrier(0);

  for (int t = 0; t < NT - 2; ++t)
    tile_body(t, icv<8>{}, icv<8>{}, bcv<true>{}, bcv<true>{});
  tile_body(NT - 2, icv<6>{}, icv<2>{},  bcv<true>{},  bcv<false>{});
  tile_body(NT - 1, icv<0>{}, icv<-1>{}, bcv<false>{}, bcv<false>{});

  const int orow0 = br + wr + ((lane >> 4) * 4);
  const int ocol0 = bc + wc_ + (lane & 15);
  #pragma unroll
  for (int m = 0; m < 8; m++){
    #pragma unroll
    for (int n = 0; n < 4; n++){
      #pragma unroll
      for (int rr = 0; rr < 4; rr++){
        int gr = orow0 + m * 16 + rr;
        int gc = ocol0 + n * 16;
        float v = acc[m][n][rr];
        size_t idx = (size_t)gr * ldc + gc;
        if (EPI == EPI_GELU)       obf[idx] = f2bf(gelu_exact(v + bcol[gc]));
        else if (EPI == EPI_GELU2) obf[idx] = f2bf(gelu_exact(v + bcol[gc] + 0.5f * brow[gr] * bcol2[gc]));
        else if (EPI == EPI_F32)   ofp[idx] = v;
        else if (EPI == EPI_ADDF32) ofp[idx] += v;
        else                       obf[idx] = f2bf(v);
      }
    }
  }
}

// ---------- 128x128 GEMM, 4 waves (2x2 of 64x64), 2 blocks/CU, 2-slab pipeline ----
template<int EPI>
__global__ __launch_bounds__(256, 2) void gemm4(const u16* __restrict__ A,
    const u16* __restrict__ BT, int K, int ldc,
    u16* __restrict__ obf, float* __restrict__ ofp){
  __shared__ __align__(16) u16 lsA[2 * 2 * 4096];   // 32KB
  __shared__ __align__(16) u16 lsB[2 * 2 * 4096];
  const int tid = threadIdx.x;
  const int lane = tid & 63;
  const int wave = tid >> 6;            // 0..3

  const u32 gx = gridDim.x;
  const u32 nwg = gx * gridDim.y;
  const u32 orig = blockIdx.y * gx + blockIdx.x;
  const u32 swzid = (orig & 7) * (nwg >> 3) + (orig >> 3);
  const int br = (int)(swzid / gx) * 128;
  const int bc = (int)(swzid % gx) * 128;

  const int wr = (wave >> 1) * 64;
  const int wc = (wave & 1) * 64;

  const int fr = lane & 15;
  const int ch = lane >> 4;
  const int p  = (fr >> 1) & 3;
  const u32 rdA = lds_off(lsA) + (u32)((wr + fr) * 64 + ((ch ^ p) * 16));
  const u32 rdB = lds_off(lsB) + (u32)((wc + fr) * 64 + ((ch ^ p) * 16));

  const int r = tid >> 2, s = tid & 3;  // r: 0..63
  const int pr = (r >> 1) & 3;
  const u32 srcA0 = (u32)(br + r) * (u32)K + (u32)((s ^ pr) * 8);
  const u32 srcA1 = (u32)(br + r + 64) * (u32)K + (u32)((s ^ pr) * 8);
  const u32 srcB0 = (u32)(bc + r) * (u32)K + (u32)((s ^ pr) * 8);
  const u32 srcB1 = (u32)(bc + r + 64) * (u32)K + (u32)((s ^ pr) * 8);
  const u32 dst0 = (u32)tid * 16u;
  const u32 dst1 = dst0 + 4096u;
  auto stA = [&](u32 kel, u32 lb){
    gload16(A + srcA0 + kel, (char*)lsA + lb + dst0);
    gload16(A + srcA1 + kel, (char*)lsA + lb + dst1);
  };
  auto stB = [&](u32 kel, u32 lb){
    gload16(BT + srcB0 + kel, (char*)lsB + lb + dst0);
    gload16(BT + srcB1 + kel, (char*)lsB + lb + dst1);
  };

  const int NT = K >> 6;
  f32x4 acc[4][4] = {};

  stA(0, 0); stB(0, 0); stA(32, 8192u); stB(32, 8192u);
  vmw<4>();
  __builtin_amdgcn_sched_barrier(0);
  __builtin_amdgcn_s_barrier();
  __builtin_amdgcn_sched_barrier(0);

  for (int t = 0; t < NT - 1; ++t){
    const u32 pb = (t & 1) ? 16384u : 0u;
    const u32 qb = pb ^ 16384u;
    const u32 kn = (u32)(t + 1) << 6;
    const u32 aA = rdA + pb, aB = rdB + pb;
    s16x8 a[4], b[4];

    stA(kn, qb); stB(kn, qb);
    a[0] = dsr<0>(aA);    a[1] = dsr<1024>(aA);
    a[2] = dsr<2048>(aA); a[3] = dsr<3072>(aA);
    b[0] = dsr<0>(aB);    b[1] = dsr<1024>(aB);
    b[2] = dsr<2048>(aB); b[3] = dsr<3072>(aB);
    lgw<0>();
    __builtin_amdgcn_sched_barrier(0);
    __builtin_amdgcn_s_setprio(1);
    #pragma unroll
    for (int m = 0; m < 4; m++)
      #pragma unroll
      for (int n = 0; n < 4; n++)
        acc[m][n] = __builtin_amdgcn_mfma_f32_16x16x32_bf16(a[m], b[n], acc[m][n], 0, 0, 0);
    __builtin_amdgcn_s_setprio(0);
    vmw<4>();
    __builtin_amdgcn_sched_barrier(0);
    __builtin_amdgcn_s_barrier();
    __builtin_amdgcn_sched_barrier(0);

    stA(kn + 32, qb + 8192u); stB(kn + 32, qb + 8192u);
    a[0] = dsr<8192>(aA);        a[1] = dsr<8192 + 1024>(aA);
    a[2] = dsr<8192 + 2048>(aA); a[3] = dsr<8192 + 3072>(aA);
    b[0] = dsr<8192>(aB);        b[1] = dsr<8192 + 1024>(aB);
    b[2] = dsr<8192 + 2048>(aB); b[3] = dsr<8192 + 3072>(aB);
    lgw<0>();
    __builtin_amdgcn_sched_barrier(0);
    __builtin_amdgcn_s_setprio(1);
    #pragma unroll
    for (int m = 0; m < 4; m++)
      #pragma unroll
      for (int n = 0; n < 4; n++)
        acc[m][n] = __builtin_amdgcn_mfma_f32_16x16x32_bf16(a[m], b[n], acc[m][n], 0, 0, 0);
    __builtin_amdgcn_s_setprio(0);
    vmw<4>();
    __builtin_amdgcn_sched_barrier(0);
    __builtin_amdgcn_s_barrier();
    __builtin_amdgcn_sched_barrier(0);
  }

  {
    const u32 pb = ((NT - 1) & 1) ? 16384u : 0u;
    const u32 aA = rdA + pb, aB = rdB + pb;
    s16x8 a[4], b[4];
    a[0] = dsr<0>(aA);    a[1] = dsr<1024>(aA);
    a[2] = dsr<2048>(aA); a[3] = dsr<3072>(aA);
    b[0] = dsr<0>(aB);    b[1] = dsr<1024>(aB);
    b[2] = dsr<2048>(aB); b[3] = dsr<3072>(aB);
    lgw<0>();
    __builtin_amdgcn_sched_barrier(0);
    #pragma unroll
    for (int m = 0; m < 4; m++)
      #pragma unroll
      for (int n = 0; n < 4; n++)
        acc[m][n] = __builtin_amdgcn_mfma_f32_16x16x32_bf16(a[m], b[n], acc[m][n], 0, 0, 0);
    vmw<0>();
    __builtin_amdgcn_sched_barrier(0);
    __builtin_amdgcn_s_barrier();
    __builtin_amdgcn_sched_barrier(0);
    a[0] = dsr<8192>(aA);        a[1] = dsr<8192 + 1024>(aA);
    a[2] = dsr<8192 + 2048>(aA); a[3] = dsr<8192 + 3072>(aA);
    b[0] = dsr<8192>(aB);        b[1] = dsr<8192 + 1024>(aB);
    b[2] = dsr<8192 + 2048>(aB); b[3] = dsr<8192 + 3072>(aB);
    lgw<0>();
    __builtin_amdgcn_sched_barrier(0);
    #pragma unroll
    for (int m = 0; m < 4; m++)
      #pragma unroll
      for (int n = 0; n < 4; n++)
        acc[m][n] = __builtin_amdgcn_mfma_f32_16x16x32_bf16(a[m], b[n], acc[m][n], 0, 0, 0);
  }

  const int orow0 = br + wr + (lane >> 4) * 4;
  const int ocol0 = bc + wc + (lane & 15);
  #pragma unroll
  for (int m = 0; m < 4; m++){
    #pragma unroll
    for (int n = 0; n < 4; n++){
      #pragma unroll
      for (int rr = 0; rr < 4; rr++){
        int gr = orow0 + m * 16 + rr;
        int gc = ocol0 + n * 16;
        float v = acc[m][n][rr];
        size_t idx = (size_t)gr * ldc + gc;
        if (EPI == EPI_BF16)      obf[idx] = f2bf(v);
        else if (EPI == EPI_F32)  ofp[idx] = v;
        else                      ofp[idx] += v;
      }
    }
  }
}

// ---------- launch ----------
extern "C" void kernel_launch(void* const* d_in, const int* in_sizes, int n_in,
                              void* d_out, int out_size, void* d_ws, size_t ws_size,
                              hipStream_t stream){
  const float* x      = (const float*)d_in[0];
  const float* HpreR  = (const float*)d_in[1];
  const float* HpostR = (const float*)d_in[2];
  const float* HresR  = (const float*)d_in[3];
  const float* W1     = (const float*)d_in[4];
  const float* b1     = (const float*)d_in[5];
  const float* W2     = (const float*)d_in[6];
  const float* b2     = (const float*)d_in[7];
  const float* gpre   = (const float*)d_in[8];
  const float* bpre   = (const float*)d_in[9];
  const float* gpost  = (const float*)d_in[10];
  const float* bpost  = (const float*)d_in[11];
  float* out = (float*)d_out;
  char* w = (char*)d_ws;
  constexpr size_t MBc = 1ull << 20;
  constexpr int KC = 5120;                // concat K = 1024 (x) + 4096 (h2)

  // w+0 is time-multiplexed: sinkhorn A0/A0T -> W1T -> H1 chunk -> VAR
  float* A0     = (float*)(w + 0);        // [1024][1024] fp32 4MB (sinkhorn phase)
  float* A0T    = (float*)(w + 4 * MBc);  // 4MB
  u16*   W1T    = (u16*)(w + 0);          // [8192][4096] bf16 64MB (after sinkhorn)
  u16*   H1     = (u16*)(w + 0);          // [4096][8192] bf16 64MB (chunked, after ET)
  float* VAR    = (float*)(w + 0);        // [8192][1024] fp32 32MB (after G3)
  u16*   W2T    = (u16*)(w + 64 * MBc);   // [4096][8192] bf16 64MB
  u16*   DPRE   = (u16*)(w + 128 * MBc);  // [1024][4096] bf16 8MB = sigmoid(HpreR)-0.5
  u16*   BCAT   = (u16*)(w + 136 * MBc);  // [1024][5120] bf16 10MB = [HresT | DPOSTT]
  u16*   XN     = (u16*)(w + 147 * MBc);  // [8192][1024] bf16 16MB
  u16*   ACAT   = (u16*)(w + 163 * MBc);  // [8192][5120] bf16 80MB = [x_bf16 | h2]
  float* S      = (float*)(w + 244 * MBc);// [8192] fp32 row sums of xn
  float* Rv     = S + 8192;               // [1024]
  float* Cv     = Rv + 1024;              // [1024]
  float* SCOL   = Cv + 1024;              // [8192] fp32 colsums of W1
  u16*   ET     = (u16*)(w + 245 * MBc);  // [8192][1024] bf16 16MB   (peak 261MB)

  dim3 blk(256);

  // ---- sinkhorn first (its scratch shares w+0 with W1T) ----
  sk_softmax_k<<<1024, blk, 0, stream>>>(HresR, A0);
  transpose_op<OPC_CAST, float><<<dim3(16, 16), blk, 0, stream>>>(A0, A0T, 1024, 1024, 1024);
  sk_fill<<<8, blk, 0, stream>>>(Rv, 2048, 1.0f);
  for (int i = 0; i < 5; i++){            // near-uniform A0: converged below fp32 eps by iter 3
    sk_pass<<<1024, blk, 0, stream>>>(A0,  Cv, Rv);   // row normalize
    sk_pass<<<1024, blk, 0, stream>>>(A0T, Rv, Cv);   // col normalize
  }
  sk_mat<<<1024, blk, 0, stream>>>(A0T, Rv, Cv, BCAT, KC);   // HresT -> BCAT cols [0,1024)

  // ---- weight precompute ----
  sk_fill<<<32, blk, 0, stream>>>(SCOL, 8192, 0.0f);
  transpose_sum<<<dim3(128, 64), blk, 0, stream>>>(W1, W1T, 4096, 8192, SCOL);
  transpose_op<OPC_CAST, u16><<<dim3(64, 128), blk, 0, stream>>>(W2, W2T, 8192, 4096, 8192);
  sig05_kernel<<<4096, blk, 0, stream>>>(HpreR, DPRE);
  // DPOSTT -> BCAT cols [1024,5120)
  transpose_op<OPC_SIG2M1, u16><<<dim3(16, 64), blk, 0, stream>>>(HpostR, BCAT + 1024, 4096, 1024, KC);

  // pre-LN: xn -> XN, bf16(x) -> ACAT cols [0,1024) (stride KC), fp32 row sums -> S
  ln1_kernel<<<8192, blk, 0, stream>>>(x, gpre, bpre, XN, ACAT, KC, S);

  // ET[k][d] = sum_h W1T[k][h] * DPRE[d][h]   (E = (sig(Hpre)-0.5)@W1, transposed)
  gemm4<EPI_BF16><<<dim3(8, 64), blk, 0, stream>>>(W1T, DPRE, 4096, 1024, ET, nullptr);

  // fused front-end, 2 chunks of 4096 rows:
  //   h1 = xn@E + 0.5*s_row*SCOL + b1 -> GELU -> H1 (chunk)
  //   h2 = GELU(H1@W2 + b2) -> ACAT cols [1024,5120) (stride KC)
  for (int c0 = 0; c0 < 2; c0++){
    const u16* xnc = XN + (size_t)c0 * 4096 * 1024;
    u16* h2c       = ACAT + (size_t)c0 * 4096 * KC + 1024;
    gemm8<EPI_GELU2><<<dim3(32, 16), dim3(512), 0, stream>>>(xnc, ET, 1024, 8192,
                                                             H1, nullptr, b1, S + c0 * 4096, SCOL);
    gemm8<EPI_GELU><<<dim3(16, 16), dim3(512), 0, stream>>>(H1, W2T, 8192, KC,
                                                            h2c, nullptr, b2, nullptr, nullptr);
  }
  // concat G4+G5: VAR = ACAT @ BCAT^T  == x@Hres + h2@(2sig(Hpost)-1), K=5120
  gemm4<EPI_F32><<<dim3(8, 64), blk, 0, stream>>>(ACAT, BCAT, KC, 1024, nullptr, VAR);
  // final LN -> fp32 out
  ln2_kernel<<<8192, blk, 0, stream>>>(VAR, gpost, bpost, out);
}

// Round 12
// 965.912 us; speedup vs baseline: 1.0175x; 1.0175x over previous
//
#include <hip/hip_runtime.h>

typedef __attribute__((ext_vector_type(4))) float f32x4;
typedef __attribute__((ext_vector_type(8))) short s16x8;
typedef unsigned short u16;
typedef unsigned int u32;

// ---------- helpers ----------
__device__ __forceinline__ u16 f2bf(float f){
  u32 u = __builtin_bit_cast(u32, f);
  u += 0x7fffu + ((u >> 16) & 1u);          // RNE
  return (u16)(u >> 16);
}
__device__ __forceinline__ float gelu_exact(float x){
  return 0.5f * x * (1.0f + erff(x * 0.70710678118654752f));
}
__device__ __forceinline__ float sigmoidf_(float x){
  return 1.0f / (1.0f + expf(-x));
}

// inline-asm LDS read: opaque to the compiler's waitcnt pass (prevents it from
// inserting vmcnt(0) drains for the global_load_lds RAW hazard).
template<int OFF>
__device__ __forceinline__ s16x8 dsr(u32 addr){
  s16x8 r;
  asm volatile("ds_read_b128 %0, %1 offset:%2" : "=v"(r) : "v"(addr), "i"(OFF));
  return r;
}
// guaranteed LDS byte offset (ptrtoint of an addrspace(3) pointer)
__device__ __forceinline__ u32 lds_off(const void* p){
  return (u32)(size_t)(const __attribute__((address_space(3))) char*)p;
}
template<int N> __device__ __forceinline__ void vmw(){
  asm volatile("s_waitcnt vmcnt(%0)" :: "n"(N) : "memory");
}
template<int N> __device__ __forceinline__ void lgw(){
  asm volatile("s_waitcnt lgkmcnt(%0)" :: "n"(N) : "memory");
}
template<int N> struct icv { static constexpr int v = N; };
template<bool B> struct bcv { static constexpr bool v = B; };

// 256-thread block reductions (4 waves)
__device__ __forceinline__ float blk_sum(float v, float* red){
  #pragma unroll
  for (int off = 32; off; off >>= 1) v += __shfl_xor(v, off, 64);
  int t = threadIdx.x;
  if ((t & 63) == 0) red[t >> 6] = v;
  __syncthreads();
  float r = red[0] + red[1] + red[2] + red[3];
  __syncthreads();
  return r;
}
__device__ __forceinline__ float blk_max(float v, float* red){
  #pragma unroll
  for (int off = 32; off; off >>= 1) v = fmaxf(v, __shfl_xor(v, off, 64));
  int t = threadIdx.x;
  if ((t & 63) == 0) red[t >> 6] = v;
  __syncthreads();
  float r = fmaxf(fmaxf(red[0], red[1]), fmaxf(red[2], red[3]));
  __syncthreads();
  return r;
}

// ---------- transpose + elementwise (fp32 in -> bf16/fp32 out), strided dest ----------
enum { OPC_CAST = 0, OPC_SIG2M1 = 2 };

template<int OP, typename OutT>
__global__ __launch_bounds__(256) void transpose_op(const float* __restrict__ in,
                                                    OutT* __restrict__ out, int R, int C,
                                                    int ldo){
  __shared__ float tile[64][65];
  const int tc = blockIdx.x, tr = blockIdx.y;
  const int c = threadIdx.x & 63, r4 = threadIdx.x >> 6;
  #pragma unroll
  for (int i = 0; i < 16; i++){
    int r = r4 * 16 + i;
    float v = in[(size_t)(tr * 64 + r) * C + tc * 64 + c];
    if (OP == OPC_SIG2M1) v = 2.0f * sigmoidf_(v) - 1.0f;
    tile[r][c] = v;
  }
  __syncthreads();
  #pragma unroll
  for (int i = 0; i < 16; i++){
    int r = r4 * 16 + i;
    float v = tile[c][r];
    size_t o = (size_t)(tc * 64 + r) * ldo + tr * 64 + c;
    if constexpr (sizeof(OutT) == 2) out[o] = f2bf(v);
    else                             out[o] = v;
  }
}

// transpose W1 [R][C] fp32 -> bf16 [C][R] AND accumulate column sums into SCOL[C]
__global__ __launch_bounds__(256) void transpose_sum(const float* __restrict__ in,
                                                     u16* __restrict__ out, int R, int C,
                                                     float* __restrict__ SCOL){
  __shared__ float tile[64][65];
  const int tc = blockIdx.x, tr = blockIdx.y;
  const int c = threadIdx.x & 63, r4 = threadIdx.x >> 6;
  float part = 0.f;
  #pragma unroll
  for (int i = 0; i < 16; i++){
    int r = r4 * 16 + i;
    float v = in[(size_t)(tr * 64 + r) * C + tc * 64 + c];
    tile[r][c] = v;
    part += v;
  }
  __syncthreads();
  #pragma unroll
  for (int i = 0; i < 16; i++){
    int r = r4 * 16 + i;
    out[(size_t)(tc * 64 + r) * R + tr * 64 + c] = f2bf(tile[c][r]);
  }
  __syncthreads();
  tile[r4][c] = part;
  __syncthreads();
  if (r4 == 0){
    float s = tile[0][c] + tile[1][c] + tile[2][c] + tile[3][c];
    atomicAdd(&SCOL[tc * 64 + c], s);
  }
}

// elementwise sigmoid(x)-0.5 -> bf16 (natural layout)
__global__ __launch_bounds__(256) void sig05_kernel(const float* __restrict__ in,
                                                    u16* __restrict__ out){
  int i = (blockIdx.x * 256 + threadIdx.x) * 4;
  const float4 v = *(const float4*)(in + i);
  ushort4 o;
  o.x = f2bf(sigmoidf_(v.x) - 0.5f); o.y = f2bf(sigmoidf_(v.y) - 0.5f);
  o.z = f2bf(sigmoidf_(v.z) - 0.5f); o.w = f2bf(sigmoidf_(v.w) - 0.5f);
  *(ushort4*)(out + i) = o;
}

__global__ __launch_bounds__(256) void sk_fill(float* p, int n, float v){
  int i = blockIdx.x * 256 + threadIdx.x;
  if (i < n) p[i] = v;
}

// ---------- sinkhorn ----------
__global__ __launch_bounds__(256) void sk_softmax_k(const float* __restrict__ raw,
                                                    float* __restrict__ A0){
  __shared__ float red[4];
  const int row = blockIdx.x, t = threadIdx.x;
  const float4 v = *(const float4*)(raw + (size_t)row * 1024 + t * 4);
  float mx = fmaxf(fmaxf(v.x, v.y), fmaxf(v.z, v.w));
  mx = blk_max(mx, red);
  float e0 = expf(v.x - mx), e1 = expf(v.y - mx), e2 = expf(v.z - mx), e3 = expf(v.w - mx);
  float s = blk_sum(e0 + e1 + e2 + e3, red);
  float sc = 1024.0f / s;
  float4 o = { e0 * sc, e1 * sc, e2 * sc, e3 * sc };
  *(float4*)(A0 + (size_t)row * 1024 + t * 4) = o;
}

// vupd[row] = vupd[row] / (vupd[row]*dot(Am[row,:], vin) + 1e-8)
__global__ __launch_bounds__(256) void sk_pass(const float* __restrict__ Am,
                                               const float* __restrict__ vin,
                                               float* __restrict__ vupd){
  __shared__ float red[4];
  const int row = blockIdx.x, t = threadIdx.x;
  const float4 a = *(const float4*)(Am + (size_t)row * 1024 + t * 4);
  const float4 b = *(const float4*)(vin + t * 4);
  float d = a.x * b.x + a.y * b.y + a.z * b.z + a.w * b.w;
  d = blk_sum(d, red);
  if (t == 0){ float rv = vupd[row]; vupd[row] = rv / (rv * d + 1e-8f); }
}

// BCAT[e][d] (stride ld) = bf16(r[d] * A0T[e][d] * c[e])
__global__ __launch_bounds__(256) void sk_mat(const float* __restrict__ A0T,
                                              const float* __restrict__ r,
                                              const float* __restrict__ c,
                                              u16* __restrict__ dst, int ld){
  const int e = blockIdx.x, t = threadIdx.x;
  const float ce = c[e];
  const float4 a  = *(const float4*)(A0T + (size_t)e * 1024 + t * 4);
  const float4 rv = *(const float4*)(r + t * 4);
  ushort4 o;
  o.x = f2bf(a.x * rv.x * ce); o.y = f2bf(a.y * rv.y * ce);
  o.z = f2bf(a.z * rv.z * ce); o.w = f2bf(a.w * rv.w * ce);
  *(ushort4*)(dst + (size_t)e * ld + t * 4) = o;
}

// ---------- layernorms ----------
__global__ __launch_bounds__(256) void ln1_kernel(const float* __restrict__ x,
    const float* __restrict__ g, const float* __restrict__ b,
    u16* __restrict__ xn, u16* __restrict__ xbf, int xstride,
    float* __restrict__ sOut){
  __shared__ float red[4];
  const int row = blockIdx.x, t = threadIdx.x;
  const float4 v = *(const float4*)(x + (size_t)row * 1024 + t * 4);
  float mu = blk_sum(v.x + v.y + v.z + v.w, red) * (1.0f / 1024.0f);
  float d0 = v.x - mu, d1 = v.y - mu, d2 = v.z - mu, d3 = v.w - mu;
  float var = blk_sum(d0 * d0 + d1 * d1 + d2 * d2 + d3 * d3, red) * (1.0f / 1024.0f);
  float rstd = rsqrtf(var + 1e-5f);
  const float4 gv = *(const float4*)(g + t * 4);
  const float4 bv = *(const float4*)(b + t * 4);
  float y0 = d0 * rstd * gv.x + bv.x;
  float y1 = d1 * rstd * gv.y + bv.y;
  float y2 = d2 * rstd * gv.z + bv.z;
  float y3 = d3 * rstd * gv.w + bv.w;
  float ss = blk_sum(y0 + y1 + y2 + y3, red);   // fp32 row-sum of xn (rank-1 epilogue term)
  if (t == 0) sOut[row] = ss;
  ushort4 o;  o.x = f2bf(y0);  o.y = f2bf(y1);  o.z = f2bf(y2);  o.w = f2bf(y3);
  *(ushort4*)(xn + (size_t)row * 1024 + t * 4) = o;
  ushort4 xo; xo.x = f2bf(v.x); xo.y = f2bf(v.y); xo.z = f2bf(v.z); xo.w = f2bf(v.w);
  *(ushort4*)(xbf + (size_t)row * xstride + t * 4) = xo;
}

__global__ __launch_bounds__(256) void ln2_kernel(const float* __restrict__ y,
    const float* __restrict__ g, const float* __restrict__ b, float* __restrict__ out){
  __shared__ float red[4];
  const int row = blockIdx.x, t = threadIdx.x;
  const float4 v = *(const float4*)(y + (size_t)row * 1024 + t * 4);
  float mu = blk_sum(v.x + v.y + v.z + v.w, red) * (1.0f / 1024.0f);
  float d0 = v.x - mu, d1 = v.y - mu, d2 = v.z - mu, d3 = v.w - mu;
  float var = blk_sum(d0 * d0 + d1 * d1 + d2 * d2 + d3 * d3, red) * (1.0f / 1024.0f);
  float rstd = rsqrtf(var + 1e-5f);
  const float4 gv = *(const float4*)(g + t * 4);
  const float4 bv = *(const float4*)(b + t * 4);
  float4 o = { d0 * rstd * gv.x + bv.x, d1 * rstd * gv.y + bv.y,
               d2 * rstd * gv.z + bv.z, d3 * rstd * gv.w + bv.w };
  *(float4*)(out + (size_t)row * 1024 + t * 4) = o;
}

enum { EPI_GELU = 1, EPI_F32 = 2, EPI_ADDF32 = 3, EPI_BF16 = 4, EPI_GELU2 = 5 };

__device__ __forceinline__ void gload16(const void* g, void* l){
  __builtin_amdgcn_global_load_lds((const __attribute__((address_space(1))) u32*)g,
                                   (__attribute__((address_space(3))) u32*)l, 16, 0, 0);
}

// ---------- 256x256 GEMM, 8 waves, deep pipeline + within-tile ds_read read-ahead ----
// (round-10 schedule — the measured optimum: 225 us, 55% MfmaUtil on G3 chunks)
template<int EPI>
__global__ __launch_bounds__(512, 2) void gemm8(const u16* __restrict__ A,
    const u16* __restrict__ BT, int K, int ldc,
    u16* __restrict__ obf, float* __restrict__ ofp,
    const float* __restrict__ bcol, const float* __restrict__ brow,
    const float* __restrict__ bcol2){
  __shared__ __align__(16) u16 lsA[2 * 256 * 64];
  __shared__ __align__(16) u16 lsB[2 * 256 * 64];
  const int tid = threadIdx.x;
  const int lane = tid & 63;
  const int wave = tid >> 6;

  // bijective XCD swizzle (all grids here are %8==0)
  const u32 gx = gridDim.x;
  const u32 nwg = gx * gridDim.y;
  const u32 orig = blockIdx.y * gx + blockIdx.x;
  const u32 swzid = (orig & 7) * (nwg >> 3) + (orig >> 3);
  const int br = (int)(swzid / gx) * 256;
  const int bc = (int)(swzid % gx) * 256;

  const int wr  = (wave >> 2) * 128;
  const int wc_ = (wave & 3) * 64;

  const int fr = lane & 15;
  const int colb0 = (lane >> 4) * 16;
  const int swz = colb0 ^ ((fr & 7) << 4);
  const u32 baseA = lds_off(lsA);
  const u32 baseB = lds_off(lsB);
  const u32 sA0 = baseA + (u32)((wr + fr) * 128 + swz);
  const u32 sA1 = baseA + (u32)((wr + fr) * 128 + (swz ^ 64));
  const u32 sB0 = baseB + (u32)((wc_ + fr) * 128 + swz);
  const u32 sB1 = baseB + (u32)((wc_ + fr) * 128 + (swz ^ 64));

  const int r = tid >> 3, s = tid & 7;
  const int lc8 = ((s ^ (r & 7)) * 8);
  const int rb_ = (r & 31) + ((r >> 5) << 6);
  const int rA[4] = { r, r + 128, r + 64, r + 192 };
  const int rB[4] = { rb_, rb_ + 128, rb_ + 32, rb_ + 160 };
  u32 srcA[4], srcB[4], dstA[4], dstB[4];
  #pragma unroll
  for (int i = 0; i < 4; i++){
    srcA[i] = (u32)(br + rA[i]) * (u32)K + (u32)lc8;
    srcB[i] = (u32)(bc + rB[i]) * (u32)K + (u32)lc8;
    dstA[i] = (u32)(rA[i] * 128 + s * 16);
    dstB[i] = (u32)(rB[i] * 128 + s * 16);
  }
  auto stA = [&](int i, u32 koff, u32 qb){ gload16(A  + srcA[i] + koff, (char*)lsA + qb + dstA[i]); };
  auto stB = [&](int i, u32 koff, u32 qb){ gload16(BT + srcB[i] + koff, (char*)lsB + qb + dstB[i]); };

  const int NT = K >> 6;
  f32x4 acc[8][4] = {};

  auto tile_body = [&](int t, auto W0_, auto W3_, auto BAR1_, auto ST0_, auto STR_){
    constexpr int  W0   = decltype(W0_)::v;
    constexpr int  W3   = decltype(W3_)::v;
    constexpr bool BAR1 = decltype(BAR1_)::v;
    constexpr bool ST0  = decltype(ST0_)::v;
    constexpr bool STR  = decltype(STR_)::v;
    const u32 pb = (t & 1) ? 32768u : 0u;
    const u32 qb = pb ^ 32768u;
    const u32 k1 = (u32)(t + 1) << 6;
    const u32 k2 = (u32)(t + 2) << 6;
    const u32 aA0 = sA0 + pb, aA1 = sA1 + pb, bB0 = sB0 + pb, bB1 = sB1 + pb;
    s16x8 a0[4][2], a1[4][2], b0[2][2], b1[2][2];

    // P0: stage {A2,A3}(t+1)->qb; issue a0+b0+b1; wait 12; MFMA Q00
    if constexpr (ST0){ stA(2, k1, qb); stA(3, k1, qb); }
    a0[0][0] = dsr<0>(aA0);    a0[0][1] = dsr<0>(aA1);
    a0[1][0] = dsr<2048>(aA0); a0[1][1] = dsr<2048>(aA1);
    a0[2][0] = dsr<4096>(aA0); a0[2][1] = dsr<4096>(aA1);
    a0[3][0] = dsr<6144>(aA0); a0[3][1] = dsr<6144>(aA1);
    b0[0][0] = dsr<0>(bB0);    b0[0][1] = dsr<0>(bB1);
    b0[1][0] = dsr<2048>(bB0); b0[1][1] = dsr<2048>(bB1);
    b1[0][0] = dsr<4096>(bB0); b1[0][1] = dsr<4096>(bB1);
    b1[1][0] = dsr<6144>(bB0); b1[1][1] = dsr<6144>(bB1);
    lgw<4>();
    __builtin_amdgcn_sched_barrier(0);
    __builtin_amdgcn_s_setprio(1);
    #pragma unroll
    for (int kk = 0; kk < 2; kk++)
      #pragma unroll
      for (int m = 0; m < 4; m++)
        #pragma unroll
        for (int n = 0; n < 2; n++)
          acc[m][n] = __builtin_amdgcn_mfma_f32_16x16x32_bf16(a0[m][kk], b0[n][kk], acc[m][n], 0, 0, 0);
    __builtin_amdgcn_s_setprio(0);
    vmw<W0>();
    __builtin_amdgcn_sched_barrier(0);
    __builtin_amdgcn_s_barrier();
    __builtin_amdgcn_sched_barrier(0);

    // P1: stage {A0,A1}(t+2)->pb; issue a1; wait b1; MFMA Q01
    if constexpr (STR){ stA(0, k2, pb); stA(1, k2, pb); }
    a1[0][0] = dsr<8192>(aA0);  a1[0][1] = dsr<8192>(aA1);
    a1[1][0] = dsr<10240>(aA0); a1[1][1] = dsr<10240>(aA1);
    a1[2][0] = dsr<12288>(aA0); a1[2][1] = dsr<12288>(aA1);
    a1[3][0] = dsr<14336>(aA0); a1[3][1] = dsr<14336>(aA1);
    lgw<8>();
    __builtin_amdgcn_sched_barrier(0);
    __builtin_amdgcn_s_setprio(1);
    #pragma unroll
    for (int kk = 0; kk < 2; kk++)
      #pragma unroll
      for (int m = 0; m < 4; m++)
        #pragma unroll
        for (int n = 0; n < 2; n++)
          acc[m][n + 2] = __builtin_amdgcn_mfma_f32_16x16x32_bf16(a0[m][kk], b1[n][kk], acc[m][n + 2], 0, 0, 0);
    __builtin_amdgcn_s_setprio(0);
    if constexpr (BAR1){
      __builtin_amdgcn_sched_barrier(0);
      __builtin_amdgcn_s_barrier();
      __builtin_amdgcn_sched_barrier(0);
    }

    // P2: stage {B0,B1}(t+2)->pb; wait a1; MFMA Q11
    if constexpr (STR){ stB(0, k2, pb); stB(1, k2, pb); }
    lgw<0>();
    __builtin_amdgcn_sched_barrier(0);
    __builtin_amdgcn_s_setprio(1);
    #pragma unroll
    for (int kk = 0; kk < 2; kk++)
      #pragma unroll
      for (int m = 0; m < 4; m++)
        #pragma unroll
        for (int n = 0; n < 2; n++)
          acc[m + 4][n + 2] = __builtin_amdgcn_mfma_f32_16x16x32_bf16(a1[m][kk], b1[n][kk], acc[m + 4][n + 2], 0, 0, 0);
    __builtin_amdgcn_s_setprio(0);
    __builtin_amdgcn_sched_barrier(0);

    // P3: stage {B2,B3}(t+2)->pb; MFMA Q10 from regs; boundary publish
    if constexpr (STR){ stB(2, k2, pb); stB(3, k2, pb); }
    __builtin_amdgcn_s_setprio(1);
    #pragma unroll
    for (int kk = 0; kk < 2; kk++)
      #pragma unroll
      for (int m = 0; m < 4; m++)
        #pragma unroll
        for (int n = 0; n < 2; n++)
          acc[m + 4][n] = __builtin_amdgcn_mfma_f32_16x16x32_bf16(a1[m][kk], b0[n][kk], acc[m + 4][n], 0, 0, 0);
    __builtin_amdgcn_s_setprio(0);
    if constexpr (W3 >= 0){
      vmw<W3>();
      __builtin_amdgcn_sched_barrier(0);
      __builtin_amdgcn_s_barrier();
      __builtin_amdgcn_sched_barrier(0);
    }
  };

  stA(0, 0, 0); stA(1, 0, 0); stB(0, 0, 0); stB(1, 0, 0);
  stB(2, 0, 0); stB(3, 0, 0); stA(2, 0, 0); stA(3, 0, 0);
  stA(0, 64, 32768u); stA(1, 64, 32768u); stB(0, 64, 32768u); stB(1, 64, 32768u);
  stB(2, 64, 32768u); stB(3, 64, 32768u);
  vmw<8>();
  __builtin_amdgcn_sched_barrier(0);
  __builtin_amdgcn_s_barrier();
  __builtin_amdgcn_sched_barrier(0);

  for (int t = 0; t < NT - 2; ++t)
    tile_body(t, icv<8>{}, icv<8>{}, bcv<true>{}, bcv<true>{}, bcv<true>{});
  tile_body(NT - 2, icv<8>{}, icv<2>{},  bcv<false>{}, bcv<true>{},  bcv<false>{});
  tile_body(NT - 1, icv<0>{}, icv<-1>{}, bcv<false>{}, bcv<false>{}, bcv<false>{});

  const int orow0 = br + wr + ((lane >> 4) * 4);
  const int ocol0 = bc + wc_ + (lane & 15);
  #pragma unroll
  for (int m = 0; m < 8; m++){
    #pragma unroll
    for (int n = 0; n < 4; n++){
      #pragma unroll
      for (int rr = 0; rr < 4; rr++){
        int gr = orow0 + m * 16 + rr;
        int gc = ocol0 + n * 16;
        float v = acc[m][n][rr];
        size_t idx = (size_t)gr * ldc + gc;
        if (EPI == EPI_GELU)       obf[idx] = f2bf(gelu_exact(v + bcol[gc]));
        else if (EPI == EPI_GELU2) obf[idx] = f2bf(gelu_exact(v + bcol[gc] + 0.5f * brow[gr] * bcol2[gc]));
        else if (EPI == EPI_F32)   ofp[idx] = v;
        else if (EPI == EPI_ADDF32) ofp[idx] += v;
        else                       obf[idx] = f2bf(v);
      }
    }
  }
}

// ---------- 128x128 GEMM, 4 waves (2x2 of 64x64), 2 blocks/CU, 2-slab pipeline ----
template<int EPI>
__global__ __launch_bounds__(256, 2) void gemm4(const u16* __restrict__ A,
    const u16* __restrict__ BT, int K, int ldc,
    u16* __restrict__ obf, float* __restrict__ ofp){
  __shared__ __align__(16) u16 lsA[2 * 2 * 4096];   // 32KB
  __shared__ __align__(16) u16 lsB[2 * 2 * 4096];
  const int tid = threadIdx.x;
  const int lane = tid & 63;
  const int wave = tid >> 6;            // 0..3

  const u32 gx = gridDim.x;
  const u32 nwg = gx * gridDim.y;
  const u32 orig = blockIdx.y * gx + blockIdx.x;
  const u32 swzid = (orig & 7) * (nwg >> 3) + (orig >> 3);
  const int br = (int)(swzid / gx) * 128;
  const int bc = (int)(swzid % gx) * 128;

  const int wr = (wave >> 1) * 64;
  const int wc = (wave & 1) * 64;

  const int fr = lane & 15;
  const int ch = lane >> 4;
  const int p  = (fr >> 1) & 3;
  const u32 rdA = lds_off(lsA) + (u32)((wr + fr) * 64 + ((ch ^ p) * 16));
  const u32 rdB = lds_off(lsB) + (u32)((wc + fr) * 64 + ((ch ^ p) * 16));

  const int r = tid >> 2, s = tid & 3;  // r: 0..63
  const int pr = (r >> 1) & 3;
  const u32 srcA0 = (u32)(br + r) * (u32)K + (u32)((s ^ pr) * 8);
  const u32 srcA1 = (u32)(br + r + 64) * (u32)K + (u32)((s ^ pr) * 8);
  const u32 srcB0 = (u32)(bc + r) * (u32)K + (u32)((s ^ pr) * 8);
  const u32 srcB1 = (u32)(bc + r + 64) * (u32)K + (u32)((s ^ pr) * 8);
  const u32 dst0 = (u32)tid * 16u;
  const u32 dst1 = dst0 + 4096u;
  auto stA = [&](u32 kel, u32 lb){
    gload16(A + srcA0 + kel, (char*)lsA + lb + dst0);
    gload16(A + srcA1 + kel, (char*)lsA + lb + dst1);
  };
  auto stB = [&](u32 kel, u32 lb){
    gload16(BT + srcB0 + kel, (char*)lsB + lb + dst0);
    gload16(BT + srcB1 + kel, (char*)lsB + lb + dst1);
  };

  const int NT = K >> 6;
  f32x4 acc[4][4] = {};

  stA(0, 0); stB(0, 0); stA(32, 8192u); stB(32, 8192u);
  vmw<4>();
  __builtin_amdgcn_sched_barrier(0);
  __builtin_amdgcn_s_barrier();
  __builtin_amdgcn_sched_barrier(0);

  for (int t = 0; t < NT - 1; ++t){
    const u32 pb = (t & 1) ? 16384u : 0u;
    const u32 qb = pb ^ 16384u;
    const u32 kn = (u32)(t + 1) << 6;
    const u32 aA = rdA + pb, aB = rdB + pb;
    s16x8 a[4], b[4];

    stA(kn, qb); stB(kn, qb);
    a[0] = dsr<0>(aA);    a[1] = dsr<1024>(aA);
    a[2] = dsr<2048>(aA); a[3] = dsr<3072>(aA);
    b[0] = dsr<0>(aB);    b[1] = dsr<1024>(aB);
    b[2] = dsr<2048>(aB); b[3] = dsr<3072>(aB);
    lgw<0>();
    __builtin_amdgcn_sched_barrier(0);
    __builtin_amdgcn_s_setprio(1);
    #pragma unroll
    for (int m = 0; m < 4; m++)
      #pragma unroll
      for (int n = 0; n < 4; n++)
        acc[m][n] = __builtin_amdgcn_mfma_f32_16x16x32_bf16(a[m], b[n], acc[m][n], 0, 0, 0);
    __builtin_amdgcn_s_setprio(0);
    vmw<4>();
    __builtin_amdgcn_sched_barrier(0);
    __builtin_amdgcn_s_barrier();
    __builtin_amdgcn_sched_barrier(0);

    stA(kn + 32, qb + 8192u); stB(kn + 32, qb + 8192u);
    a[0] = dsr<8192>(aA);        a[1] = dsr<8192 + 1024>(aA);
    a[2] = dsr<8192 + 2048>(aA); a[3] = dsr<8192 + 3072>(aA);
    b[0] = dsr<8192>(aB);        b[1] = dsr<8192 + 1024>(aB);
    b[2] = dsr<8192 + 2048>(aB); b[3] = dsr<8192 + 3072>(aB);
    lgw<0>();
    __builtin_amdgcn_sched_barrier(0);
    __builtin_amdgcn_s_setprio(1);
    #pragma unroll
    for (int m = 0; m < 4; m++)
      #pragma unroll
      for (int n = 0; n < 4; n++)
        acc[m][n] = __builtin_amdgcn_mfma_f32_16x16x32_bf16(a[m], b[n], acc[m][n], 0, 0, 0);
    __builtin_amdgcn_s_setprio(0);
    vmw<4>();
    __builtin_amdgcn_sched_barrier(0);
    __builtin_amdgcn_s_barrier();
    __builtin_amdgcn_sched_barrier(0);
  }

  {
    const u32 pb = ((NT - 1) & 1) ? 16384u : 0u;
    const u32 aA = rdA + pb, aB = rdB + pb;
    s16x8 a[4], b[4];
    a[0] = dsr<0>(aA);    a[1] = dsr<1024>(aA);
    a[2] = dsr<2048>(aA); a[3] = dsr<3072>(aA);
    b[0] = dsr<0>(aB);    b[1] = dsr<1024>(aB);
    b[2] = dsr<2048>(aB); b[3] = dsr<3072>(aB);
    lgw<0>();
    __builtin_amdgcn_sched_barrier(0);
    #pragma unroll
    for (int m = 0; m < 4; m++)
      #pragma unroll
      for (int n = 0; n < 4; n++)
        acc[m][n] = __builtin_amdgcn_mfma_f32_16x16x32_bf16(a[m], b[n], acc[m][n], 0, 0, 0);
    vmw<0>();
    __builtin_amdgcn_sched_barrier(0);
    __builtin_amdgcn_s_barrier();
    __builtin_amdgcn_sched_barrier(0);
    a[0] = dsr<8192>(aA);        a[1] = dsr<8192 + 1024>(aA);
    a[2] = dsr<8192 + 2048>(aA); a[3] = dsr<8192 + 3072>(aA);
    b[0] = dsr<8192>(aB);        b[1] = dsr<8192 + 1024>(aB);
    b[2] = dsr<8192 + 2048>(aB); b[3] = dsr<8192 + 3072>(aB);
    lgw<0>();
    __builtin_amdgcn_sched_barrier(0);
    #pragma unroll
    for (int m = 0; m < 4; m++)
      #pragma unroll
      for (int n = 0; n < 4; n++)
        acc[m][n] = __builtin_amdgcn_mfma_f32_16x16x32_bf16(a[m], b[n], acc[m][n], 0, 0, 0);
  }

  const int orow0 = br + wr + (lane >> 4) * 4;
  const int ocol0 = bc + wc + (lane & 15);
  #pragma unroll
  for (int m = 0; m < 4; m++){
    #pragma unroll
    for (int n = 0; n < 4; n++){
      #pragma unroll
      for (int rr = 0; rr < 4; rr++){
        int gr = orow0 + m * 16 + rr;
        int gc = ocol0 + n * 16;
        float v = acc[m][n][rr];
        size_t idx = (size_t)gr * ldc + gc;
        if (EPI == EPI_BF16)      obf[idx] = f2bf(v);
        else if (EPI == EPI_F32)  ofp[idx] = v;
        else                      ofp[idx] += v;
      }
    }
  }
}

// ---------- launch ----------
extern "C" void kernel_launch(void* const* d_in, const int* in_sizes, int n_in,
                              void* d_out, int out_size, void* d_ws, size_t ws_size,
                              hipStream_t stream){
  const float* x      = (const float*)d_in[0];
  const float* HpreR  = (const float*)d_in[1];
  const float* HpostR = (const float*)d_in[2];
  const float* HresR  = (const float*)d_in[3];
  const float* W1     = (const float*)d_in[4];
  const float* b1     = (const float*)d_in[5];
  const float* W2     = (const float*)d_in[6];
  const float* b2     = (const float*)d_in[7];
  const float* gpre   = (const float*)d_in[8];
  const float* bpre   = (const float*)d_in[9];
  const float* gpost  = (const float*)d_in[10];
  const float* bpost  = (const float*)d_in[11];
  float* out = (float*)d_out;
  char* w = (char*)d_ws;
  constexpr size_t MBc = 1ull << 20;
  constexpr int KC = 5120;                // concat K = 1024 (x) + 4096 (h2)

  // w+0 is time-multiplexed: sinkhorn A0/A0T -> W1T -> H1 chunk -> VAR
  float* A0     = (float*)(w + 0);        // [1024][1024] fp32 4MB (sinkhorn phase)
  float* A0T    = (float*)(w + 4 * MBc);  // 4MB
  u16*   W1T    = (u16*)(w + 0);          // [8192][4096] bf16 64MB (after sinkhorn)
  u16*   H1     = (u16*)(w + 0);          // [4096][8192] bf16 64MB (chunked, after ET)
  float* VAR    = (float*)(w + 0);        // [8192][1024] fp32 32MB (after G3)
  u16*   W2T    = (u16*)(w + 64 * MBc);   // [4096][8192] bf16 64MB
  u16*   DPRE   = (u16*)(w + 128 * MBc);  // [1024][4096] bf16 8MB = sigmoid(HpreR)-0.5
  u16*   BCAT   = (u16*)(w + 136 * MBc);  // [1024][5120] bf16 10MB = [HresT | DPOSTT]
  u16*   XN     = (u16*)(w + 147 * MBc);  // [8192][1024] bf16 16MB
  u16*   ACAT   = (u16*)(w + 163 * MBc);  // [8192][5120] bf16 80MB = [x_bf16 | h2]
  float* S      = (float*)(w + 244 * MBc);// [8192] fp32 row sums of xn
  float* Rv     = S + 8192;               // [1024]
  float* Cv     = Rv + 1024;              // [1024]
  float* SCOL   = Cv + 1024;              // [8192] fp32 colsums of W1
  u16*   ET     = (u16*)(w + 245 * MBc);  // [8192][1024] bf16 16MB   (peak 261MB)

  dim3 blk(256);

  // ---- sinkhorn first (its scratch shares w+0 with W1T) ----
  sk_softmax_k<<<1024, blk, 0, stream>>>(HresR, A0);
  transpose_op<OPC_CAST, float><<<dim3(16, 16), blk, 0, stream>>>(A0, A0T, 1024, 1024, 1024);
  sk_fill<<<8, blk, 0, stream>>>(Rv, 2048, 1.0f);
  for (int i = 0; i < 5; i++){            // near-uniform A0: converged below fp32 eps by iter 3
    sk_pass<<<1024, blk, 0, stream>>>(A0,  Cv, Rv);   // row normalize
    sk_pass<<<1024, blk, 0, stream>>>(A0T, Rv, Cv);   // col normalize
  }
  sk_mat<<<1024, blk, 0, stream>>>(A0T, Rv, Cv, BCAT, KC);   // HresT -> BCAT cols [0,1024)

  // ---- weight precompute ----
  sk_fill<<<32, blk, 0, stream>>>(SCOL, 8192, 0.0f);
  transpose_sum<<<dim3(128, 64), blk, 0, stream>>>(W1, W1T, 4096, 8192, SCOL);
  transpose_op<OPC_CAST, u16><<<dim3(64, 128), blk, 0, stream>>>(W2, W2T, 8192, 4096, 8192);
  sig05_kernel<<<4096, blk, 0, stream>>>(HpreR, DPRE);
  // DPOSTT -> BCAT cols [1024,5120)
  transpose_op<OPC_SIG2M1, u16><<<dim3(16, 64), blk, 0, stream>>>(HpostR, BCAT + 1024, 4096, 1024, KC);

  // pre-LN: xn -> XN, bf16(x) -> ACAT cols [0,1024) (stride KC), fp32 row sums -> S
  ln1_kernel<<<8192, blk, 0, stream>>>(x, gpre, bpre, XN, ACAT, KC, S);

  // ET[k][d] = sum_h W1T[k][h] * DPRE[d][h]   (E = (sig(Hpre)-0.5)@W1, transposed)
  gemm4<EPI_BF16><<<dim3(8, 64), blk, 0, stream>>>(W1T, DPRE, 4096, 1024, ET, nullptr);

  // fused front-end, 2 chunks of 4096 rows:
  //   h1 = xn@E + 0.5*s_row*SCOL + b1 -> GELU -> H1 (chunk)
  //   h2 = GELU(H1@W2 + b2) -> ACAT cols [1024,5120) (stride KC)
  for (int c0 = 0; c0 < 2; c0++){
    const u16* xnc = XN + (size_t)c0 * 4096 * 1024;
    u16* h2c       = ACAT + (size_t)c0 * 4096 * KC + 1024;
    gemm8<EPI_GELU2><<<dim3(32, 16), dim3(512), 0, stream>>>(xnc, ET, 1024, 8192,
                                                             H1, nullptr, b1, S + c0 * 4096, SCOL);
    gemm8<EPI_GELU><<<dim3(16, 16), dim3(512), 0, stream>>>(H1, W2T, 8192, KC,
                                                            h2c, nullptr, b2, nullptr, nullptr);
  }
  // concat G4+G5: VAR = ACAT @ BCAT^T  == x@Hres + h2@(2sig(Hpost)-1), K=5120
  gemm4<EPI_F32><<<dim3(8, 64), blk, 0, stream>>>(ACAT, BCAT, KC, 1024, nullptr, VAR);
  // final LN -> fp32 out
  ln2_kernel<<<8192, blk, 0, stream>>>(VAR, gpost, bpost, out);
}